// Round 17
// baseline (2711.059 us; speedup 1.0000x reference)
//
#include <hip/hip_runtime.h>
#include <hip/hip_bf16.h>

#define NI 768
#define NJ 768
#define CN 512
#define CP 128
#define NH 8
#define CH 32
#define HC 256   // NH*CH
#define NSTR 6
#define SJ 128

typedef float  fx4  __attribute__((ext_vector_type(4)));
typedef float  fx2  __attribute__((ext_vector_type(2)));
typedef short  bv8  __attribute__((ext_vector_type(8)));
typedef unsigned short usx4 __attribute__((ext_vector_type(4)));

__device__ __forceinline__ short f2bf(float f) {
    __hip_bfloat16 h = __float2bfloat16(f);
    return *reinterpret_cast<short*>(&h);
}
__device__ __forceinline__ float bf2f(unsigned short u) {
    union { unsigned int u; float f; } c; c.u = ((unsigned int)u) << 16; return c.f;
}

struct NodeS { float xs[8][CN]; float red[4][8][2]; };
struct PairS { unsigned short wcatT[16][136]; float redS[16][16]; float redC[16][16];
               float scalS[16]; float scalC[16]; unsigned short sb[8][68]; };
struct AttnS { unsigned short P[32][136]; float sumbuf[4][32]; };
struct CombS { float ogl[2][HC]; };
union SmemU { NodeS n; PairS p; AttnS a; CombS c; };

// Counters in ctr[]: [0]=claim, [1]=node done (192), [2+ix]=pair done per row-tile
// (384 each), [26+ix]=attn done per row-tile (48 each).
// Unit order: 192 node | per ix: 384 pair, 48 attn | 384 combine. Claims are
// start-ordered => any spinner's deps were claimed earlier => no deadlock.
__global__ __launch_bounds__(256) void wq_kernel(
    const float* __restrict__ node_i, const float* __restrict__ node_j,
    const float* __restrict__ ln_i_w, const float* __restrict__ ln_i_b,
    const float* __restrict__ ln_j_w, const float* __restrict__ ln_j_b,
    const float* __restrict__ Wq, const float* __restrict__ Wk,
    const float* __restrict__ Wv, const float* __restrict__ Wg,
    const float* __restrict__ bg,
    const float* __restrict__ lnpw, const float* __restrict__ lnpb,
    const float* __restrict__ Wpb, const float* __restrict__ bpb,
    const float* __restrict__ Wpg, const float* __restrict__ bpg,
    const float* __restrict__ pair, const float* __restrict__ pmask,
    const float* __restrict__ mi,
    const float* __restrict__ Wo, const float* __restrict__ bo,
    float* __restrict__ qx, unsigned short* __restrict__ qsb,
    unsigned short* __restrict__ ksb, unsigned short* __restrict__ vtb,
    float* __restrict__ gs, unsigned short* __restrict__ biasb,
    float* __restrict__ pnum, float* __restrict__ pden,
    float* __restrict__ outp, unsigned int* __restrict__ ctr)
{
    __shared__ SmemU sm;
    __shared__ int s_unit;
    const int t = threadIdx.x;
    if (t == 0) s_unit = (int)atomicAdd(&ctr[0], 1u);
    __syncthreads();
    const int u = s_unit;
    const int lane = t & 63, wave = t >> 6;
    const int o = lane & 15, kq = lane >> 4;

    if (u < 192) {
        // ================= node unit =================
        const bool isj = u >= 96;
        const int r0 = (isj ? u - 96 : u) * 8;
        const float* xin = isj ? node_j : node_i;
        const float* lw = isj ? ln_j_w : ln_i_w;
        const float* lb = isj ? ln_j_b : ln_i_b;

        fx2 vrow[8]; float s8[8], q8[8];
#pragma unroll
        for (int r = 0; r < 8; ++r) {
            vrow[r] = *(const fx2*)(xin + (size_t)(r0 + r) * CN + t * 2);
            s8[r] = vrow[r][0] + vrow[r][1];
            q8[r] = vrow[r][0] * vrow[r][0] + vrow[r][1] * vrow[r][1];
        }
#pragma unroll
        for (int d = 1; d < 64; d <<= 1)
#pragma unroll
            for (int r = 0; r < 8; ++r) {
                s8[r] += __shfl_xor(s8[r], d);
                q8[r] += __shfl_xor(q8[r], d);
            }
        if ((t & 63) == 0)
#pragma unroll
            for (int r = 0; r < 8; ++r) { sm.n.red[wave][r][0] = s8[r]; sm.n.red[wave][r][1] = q8[r]; }
        __syncthreads();
        fx2 lwv = *(const fx2*)(lw + t * 2), lbv = *(const fx2*)(lb + t * 2);
#pragma unroll
        for (int r = 0; r < 8; ++r) {
            float s = sm.n.red[0][r][0] + sm.n.red[1][r][0] + sm.n.red[2][r][0] + sm.n.red[3][r][0];
            float q = sm.n.red[0][r][1] + sm.n.red[1][r][1] + sm.n.red[2][r][1] + sm.n.red[3][r][1];
            float mean = s * (1.f / CN);
            float var = q * (1.f / CN) - mean * mean;
            float rs = rsqrtf(var + 1e-5f);
            fx2 ov;
            ov[0] = (vrow[r][0] - mean) * rs * lwv[0] + lbv[0];
            ov[1] = (vrow[r][1] - mean) * rs * lwv[1] + lbv[1];
            sm.n.xs[r][t * 2] = ov[0]; sm.n.xs[r][t * 2 + 1] = ov[1];
            if (!isj) *(fx2*)(qx + (size_t)(r0 + r) * CN + t * 2) = ov;
        }
        __syncthreads();

        for (int m = 0; m < 2; ++m) {
            const float* W = isj ? (m ? Wv : Wk) : (m ? Wg : Wq);
            float acc[8] = {0.f,0.f,0.f,0.f,0.f,0.f,0.f,0.f};
            for (int cc = 0; cc < CN; cc += 4) {
                fx4 xv[8];
#pragma unroll
                for (int r = 0; r < 8; ++r) xv[r] = *(const fx4*)&sm.n.xs[r][cc];
#pragma unroll
                for (int uu = 0; uu < 4; ++uu) {
                    float w = W[(size_t)(cc + uu) * HC + t];
#pragma unroll
                    for (int r = 0; r < 8; ++r) acc[r] = fmaf(xv[r][uu], w, acc[r]);
                }
            }
            if (!isj) {
                if (m == 0) {
#pragma unroll
                    for (int r = 0; r < 8; ++r)
                        qsb[(size_t)(r0 + r) * HC + t] =
                            (unsigned short)f2bf(acc[r] * 0.17677669529663687f);
                } else {
#pragma unroll
                    for (int r = 0; r < 8; ++r)
                        gs[(size_t)(r0 + r) * HC + t] =
                            1.f / (1.f + __expf(-(acc[r] + bg[t])));
                }
            } else {
                if (m == 0) {
#pragma unroll
                    for (int r = 0; r < 8; ++r)
                        ksb[(size_t)(r0 + r) * HC + t] = (unsigned short)f2bf(acc[r]);
                } else {
                    bv8 vv;
#pragma unroll
                    for (int r = 0; r < 8; ++r) vv[r] = f2bf(acc[r]);
                    *(bv8*)&vtb[(size_t)t * NJ + r0] = vv;
                }
            }
        }
        __threadfence();
        __syncthreads();
        if (t == 0) __hip_atomic_fetch_add(&ctr[1], 1u, __ATOMIC_RELEASE, __HIP_MEMORY_SCOPE_AGENT);
        return;
    }

    if (u < 10560) {
        const int v = u - 192;
        const int ix = v / 432;
        const int s = v % 432;
        if (s < 384) {
            // ================= pair unit: one i x 64 j =================
            const int i    = ix * 32 + s / 12;
            const int jt64 = (s % 12) * 64;
            const int jt   = jt64 + wave * 16;

            const float* prow = pair + ((size_t)i * NJ + (jt + o)) * CP + kq * 8;
            fx4 x0[4], x1[4];
#pragma unroll
            for (int ss = 0; ss < 4; ++ss) {
                x0[ss] = *(const fx4*)(prow + ss * 32);
                x1[ss] = *(const fx4*)(prow + ss * 32 + 4);
            }

            {
                const int oo = t & 15, cgi = t >> 4;
                float pS = 0.f, pC = 0.f;
#pragma unroll
                for (int e = 0; e < 8; ++e) {
                    int c = cgi * 8 + e;
                    float w = (oo < 8) ? Wpb[c * 8 + oo] : Wpg[c * 8 + (oo - 8)];
                    float wv = lnpw[c] * w;
                    short b = f2bf(wv);
                    sm.p.wcatT[oo][c] = (unsigned short)b;
                    pS += bf2f((unsigned short)b);
                    pC += lnpb[c] * w;
                }
                sm.p.redS[cgi][oo] = pS; sm.p.redC[cgi][oo] = pC;
                __syncthreads();
                if (t < 16) {
                    float s2 = 0.f, c2 = 0.f;
#pragma unroll
                    for (int k = 0; k < 16; ++k) { s2 += sm.p.redS[k][t]; c2 += sm.p.redC[k][t]; }
                    sm.p.scalS[t] = s2;
                    sm.p.scalC[t] = c2 + ((t < 8) ? bpb[t] : bpg[t - 8]);
                }
                __syncthreads();
            }

            bv8 bfrag[4];
#pragma unroll
            for (int ss = 0; ss < 4; ++ss)
                bfrag[ss] = *(const bv8*)&sm.p.wcatT[o][ss * 32 + kq * 8];
            const float spb = sm.p.scalS[o];
            const float cpb = sm.p.scalC[o];

            bv8 afrag[4];
#pragma unroll
            for (int ss = 0; ss < 4; ++ss) {
#pragma unroll
                for (int uu = 0; uu < 4; ++uu) {
                    afrag[ss][uu]     = f2bf(x0[ss][uu]);
                    afrag[ss][uu + 4] = f2bf(x1[ss][uu]);
                }
            }
            bv8 ones;
#pragma unroll
            for (int uu = 0; uu < 8; ++uu) ones[uu] = (short)0x3F80;

            fx4 acc  = {0.f, 0.f, 0.f, 0.f};
            fx4 accS = {0.f, 0.f, 0.f, 0.f};
            fx4 accG = {0.f, 0.f, 0.f, 0.f};
#pragma unroll
            for (int ss = 0; ss < 4; ++ss) {
                acc  = __builtin_amdgcn_mfma_f32_16x16x32_bf16(afrag[ss], bfrag[ss], acc,  0, 0, 0);
                accS = __builtin_amdgcn_mfma_f32_16x16x32_bf16(afrag[ss], ones,      accS, 0, 0, 0);
                accG = __builtin_amdgcn_mfma_f32_16x16x32_bf16(afrag[ss], afrag[ss], accG, 0, 0, 0);
            }

#pragma unroll
            for (int r = 0; r < 4; ++r) {
                const int p = kq * 4 + r;
                float sp = accS[r];
                float qp = __shfl(accG[r], kq * 20 + r);
                float mean = sp * (1.f / CP);
                float var  = qp * (1.f / CP) - mean * mean;
                float rstd = rsqrtf(var + 1e-5f);
                float pre  = rstd * (acc[r] - mean * spb) + cpb;
                float part = __shfl_xor(pre, 8);
                if (o < 8) {
                    float sig = 1.f / (1.f + __expf(-part));
                    int j = jt + p;
                    float b = pre * sig + (pmask[(size_t)i * NJ + j] - 1.f) * 1.0e9f;
                    sm.p.sb[o][wave * 16 + p] = (unsigned short)f2bf(b);
                }
            }
            __syncthreads();
            if (t < 128) {
                const int oo = t >> 4, ck = t & 15;
                usx4 vv;
#pragma unroll
                for (int uu = 0; uu < 4; ++uu) vv[uu] = sm.p.sb[oo][ck * 4 + uu];
                *(usx4*)&biasb[((size_t)oo * NI + i) * NJ + jt64 + ck * 4] = vv;
            }
            __threadfence();
            __syncthreads();
            if (t == 0) __hip_atomic_fetch_add(&ctr[2 + ix], 1u, __ATOMIC_RELEASE, __HIP_MEMORY_SCOPE_AGENT);
            return;
        }

        // ================= attn unit =================
        const int s2 = s - 384;
        const int h = s2 / NSTR;
        const int jz = s2 % NSTR;
        const int i0 = ix * 32;
        const int jbase = jz * SJ;
        const int pb = (ix * NH + h) * NSTR + jz;
        const int rowl = o, g = kq;
        const int w = wave;

        if (t == 0) {
            while (__hip_atomic_load(&ctr[2 + ix], __ATOMIC_ACQUIRE, __HIP_MEMORY_SCOPE_AGENT) < 384u ||
                   __hip_atomic_load(&ctr[1], __ATOMIC_ACQUIRE, __HIP_MEMORY_SCOPE_AGENT) < 192u)
                __builtin_amdgcn_s_sleep(8);
        }
        __syncthreads();

        bv8 aq[2];
#pragma unroll
        for (int it = 0; it < 2; ++it)
            aq[it] = *(const bv8*)&qsb[(size_t)(i0 + it * 16 + rowl) * HC + h * CH + g * 8];

        bv8 bk[2];
#pragma unroll
        for (int jt = 0; jt < 2; ++jt) {
            const int jb = jbase + w * 32 + jt * 16;
            bk[jt] = *(const bv8*)&ksb[(size_t)(jb + rowl) * HC + h * CH + g * 8];
        }
        const unsigned short* bbase = biasb + (size_t)h * NI * NJ;
        unsigned short bl[2][2][4];
#pragma unroll
        for (int jt = 0; jt < 2; ++jt) {
            const int jb = jbase + w * 32 + jt * 16;
#pragma unroll
            for (int it = 0; it < 2; ++it)
#pragma unroll
                for (int r = 0; r < 4; ++r) {
                    const int il = it * 16 + g * 4 + r;
                    bl[jt][it][r] = bbase[(size_t)(i0 + il) * NJ + jb + rowl];
                }
        }

        float rs[2][4] = {{0.f,0.f,0.f,0.f},{0.f,0.f,0.f,0.f}};
#pragma unroll
        for (int jt = 0; jt < 2; ++jt) {
            const int jloc = w * 32 + jt * 16;
#pragma unroll
            for (int it = 0; it < 2; ++it) {
                fx4 acc = {0.f, 0.f, 0.f, 0.f};
                acc = __builtin_amdgcn_mfma_f32_16x16x32_bf16(aq[it], bk[jt], acc, 0, 0, 0);
#pragma unroll
                for (int r = 0; r < 4; ++r) {
                    const int il = it * 16 + g * 4 + r;
                    float s3 = acc[r] + bf2f(bl[jt][it][r]);
                    float p = __expf(s3);
                    rs[it][r] += p;
                    sm.a.P[il][jloc + rowl] = (unsigned short)f2bf(p);
                }
            }
        }
#pragma unroll
        for (int it = 0; it < 2; ++it)
#pragma unroll
            for (int r = 0; r < 4; ++r) {
                float vv = rs[it][r];
                vv += __shfl_xor(vv, 1); vv += __shfl_xor(vv, 2);
                vv += __shfl_xor(vv, 4); vv += __shfl_xor(vv, 8);
                rs[it][r] = vv;
            }
        if (rowl == 0) {
#pragma unroll
            for (int it = 0; it < 2; ++it)
#pragma unroll
                for (int r = 0; r < 4; ++r)
                    sm.a.sumbuf[w][it * 16 + g * 4 + r] = rs[it][r];
        }

        const int it2 = w & 1, ct = w >> 1;
        bv8 vv4[4];
#pragma unroll
        for (int kk = 0; kk < 4; ++kk)
            vv4[kk] = *(const bv8*)&vtb[(size_t)(h * CH + ct * 16 + rowl) * NJ + jbase + kk * 32 + g * 8];

        __syncthreads();

        if (t < 32)
            pden[(size_t)pb * 32 + t] =
                sm.a.sumbuf[0][t] + sm.a.sumbuf[1][t] + sm.a.sumbuf[2][t] + sm.a.sumbuf[3][t];

        fx4 acc = {0.f, 0.f, 0.f, 0.f};
#pragma unroll
        for (int kk = 0; kk < 4; ++kk) {
            bv8 ap = *(const bv8*)&sm.a.P[it2 * 16 + rowl][kk * 32 + g * 8];
            acc = __builtin_amdgcn_mfma_f32_16x16x32_bf16(ap, vv4[kk], acc, 0, 0, 0);
        }
#pragma unroll
        for (int r = 0; r < 4; ++r) {
            const int il = it2 * 16 + g * 4 + r;
            pnum[(size_t)pb * 1024 + il * 32 + ct * 16 + rowl] = acc[r];
        }
        __threadfence();
        __syncthreads();
        if (t == 0) __hip_atomic_fetch_add(&ctr[26 + ix], 1u, __ATOMIC_RELEASE, __HIP_MEMORY_SCOPE_AGENT);
        return;
    }

    // ================= combine unit =================
    {
        const int cu = u - 10560;
        const int r0 = cu * 2;
        const int ix = r0 >> 5;
        if (t == 0) {
            while (__hip_atomic_load(&ctr[26 + ix], __ATOMIC_ACQUIRE, __HIP_MEMORY_SCOPE_AGENT) < 48u)
                __builtin_amdgcn_s_sleep(8);
        }
        __syncthreads();

        const int h = t >> 5, c = t & 31;
#pragma unroll
        for (int r = 0; r < 2; ++r) {
            const int i = r0 + r;
            const int pb = ((i >> 5) * NH + h) * NSTR;
            const int il = i & 31;
            float n = 0.f, d = 0.f;
#pragma unroll
            for (int ss = 0; ss < NSTR; ++ss) {
                n += pnum[(size_t)(pb + ss) * 1024 + il * 32 + c];
                d += pden[(size_t)(pb + ss) * 32 + il];
            }
            sm.c.ogl[r][t] = n / d * gs[(size_t)i * HC + t];
        }
        __syncthreads();

        float acc[2][2] = {{0,0},{0,0}};
        for (int cc = 0; cc < HC; cc += 4) {
            fx4 xr0 = *(const fx4*)&sm.c.ogl[0][cc];
            fx4 xr1 = *(const fx4*)&sm.c.ogl[1][cc];
#pragma unroll
            for (int uu = 0; uu < 4; ++uu) {
                float w0 = Wo[(size_t)(cc + uu) * CN + t];
                float w1 = Wo[(size_t)(cc + uu) * CN + 256 + t];
                acc[0][0] = fmaf(xr0[uu], w0, acc[0][0]); acc[0][1] = fmaf(xr0[uu], w1, acc[0][1]);
                acc[1][0] = fmaf(xr1[uu], w0, acc[1][0]); acc[1][1] = fmaf(xr1[uu], w1, acc[1][1]);
            }
        }
#pragma unroll
        for (int r = 0; r < 2; ++r) {
            float mk = mi[r0 + r];
            size_t base = (size_t)(r0 + r) * CN;
            outp[base + t]       = qx[base + t]       + (acc[r][0] + bo[t])       * mk;
            outp[base + 256 + t] = qx[base + 256 + t] + (acc[r][1] + bo[t + 256]) * mk;
        }
    }
}

// ---------------------------------------------------------------- launch
extern "C" void kernel_launch(void* const* d_in, const int* in_sizes, int n_in,
                              void* d_out, int out_size, void* d_ws, size_t ws_size,
                              hipStream_t stream)
{
    const float* node_i = (const float*)d_in[0];
    const float* node_j = (const float*)d_in[1];
    const float* pair   = (const float*)d_in[2];
    const float* pmask  = (const float*)d_in[3];
    const float* nmask  = (const float*)d_in[4];
    const float* ln_i_w = (const float*)d_in[5];
    const float* ln_i_b = (const float*)d_in[6];
    const float* ln_j_w = (const float*)d_in[7];
    const float* ln_j_b = (const float*)d_in[8];
    const float* ln_p_w = (const float*)d_in[9];
    const float* ln_p_b = (const float*)d_in[10];
    const float* W_pb   = (const float*)d_in[11];
    const float* b_pb   = (const float*)d_in[12];
    const float* W_pg   = (const float*)d_in[13];
    const float* b_pg   = (const float*)d_in[14];
    const float* Wq     = (const float*)d_in[15];
    const float* Wk     = (const float*)d_in[16];
    const float* Wv     = (const float*)d_in[17];
    const float* Wg     = (const float*)d_in[18];
    const float* bg     = (const float*)d_in[19];
    const float* Wo     = (const float*)d_in[20];
    const float* bo     = (const float*)d_in[21];
    float* outp = (float*)d_out;

    unsigned int* ctr = (unsigned int*)d_ws;       // 64 uints (256 B)
    float* fw = (float*)d_ws + 64;
    float* qx   = fw;                              // [NI][CN]
    float* gs   = qx + (size_t)NI * CN;            // [NI][HC]
    float* pnum = gs + (size_t)NI * HC;            // [24*8*6][1024]
    float* pden = pnum + (size_t)24 * NH * NSTR * 1024; // [24*8*6][32]
    unsigned short* qsb = (unsigned short*)(pden + (size_t)24 * NH * NSTR * 32);
    unsigned short* ksb = qsb + (size_t)NI * HC;
    unsigned short* vtb = ksb + (size_t)NJ * HC;
    unsigned short* biasb = vtb + (size_t)HC * NJ;

    hipMemsetAsync(d_ws, 0, 256, stream);
    hipLaunchKernelGGL(wq_kernel, dim3(192 + 24 * 432 + NI / 2), dim3(256), 0, stream,
                       node_i, node_j, ln_i_w, ln_i_b, ln_j_w, ln_j_b,
                       Wq, Wk, Wv, Wg, bg,
                       ln_p_w, ln_p_b, W_pb, b_pb, W_pg, b_pg,
                       pair, pmask, nmask, Wo, bo,
                       qx, qsb, ksb, vtb, gs, biasb, pnum, pden, outp, ctr);
}